// Round 4
// baseline (669.695 us; speedup 1.0000x reference)
//
#include <hip/hip_runtime.h>

#define C128 128

typedef __attribute__((ext_vector_type(2))) float f32x2;
typedef __attribute__((ext_vector_type(4))) float f32x4;
typedef __attribute__((ext_vector_type(8))) short short8;

// f32 -> bf16 with round-to-nearest-even (finite inputs only)
__device__ __forceinline__ short f2bf(float f) {
  union { float f; unsigned u; } v; v.f = f;
  unsigned r = (v.u + 0x7fffu + ((v.u >> 16) & 1u)) >> 16;
  return (short)r;
}

// out[r][j] = sum_k A[r][k] * W[j][k]  (+ add[r][j]) (+ gtab[gidx[r]][j])
// Tile: 64 rows x 128 cols per block; 4 waves, each wave owns 16 rows x 128 cols.
// MFMA 16x16x32 bf16. A-frag: row = lane&15, k = (lane>>4)*8 + i.
// D: col = lane&15, row = (lane>>4)*4 + reg.
// In-place safe for out==A: each wave reads only the 16 rows it later writes,
// and all A reads precede all stores within the wave.
__global__ __launch_bounds__(256) void gemm_wt_fused(
    const float* __restrict__ A, const float* __restrict__ W,
    const float* __restrict__ add,
    const int* __restrict__ gidx, const float* __restrict__ gtab,
    float* __restrict__ out, int R)
{
  const int tid  = threadIdx.x;
  const int wave = tid >> 6;
  const int lane = tid & 63;
  const int r16  = lane & 15;
  const int kg   = lane >> 4;

  const int rowbase = blockIdx.x * 64 + wave * 16;
  const int arow_i  = rowbase + r16;
  const int lrow    = arow_i < R ? arow_i : (R - 1);  // clamp; garbage rows never stored

  f32x4 acc[8];
#pragma unroll
  for (int i = 0; i < 8; ++i) acc[i] = (f32x4){0.f, 0.f, 0.f, 0.f};

  const float* arow = A + (long long)lrow * C128;

#pragma unroll
  for (int ks = 0; ks < 4; ++ks) {
    const int k0 = ks * 32 + kg * 8;
    f32x4 alo = *(const f32x4*)(arow + k0);
    f32x4 ahi = *(const f32x4*)(arow + k0 + 4);
    short8 af;
    af[0] = f2bf(alo.x); af[1] = f2bf(alo.y);
    af[2] = f2bf(alo.z); af[3] = f2bf(alo.w);
    af[4] = f2bf(ahi.x); af[5] = f2bf(ahi.y);
    af[6] = f2bf(ahi.z); af[7] = f2bf(ahi.w);
#pragma unroll
    for (int nf = 0; nf < 8; ++nf) {
      const float* wrow = W + (nf * 16 + r16) * C128 + k0;
      f32x4 wlo = *(const f32x4*)(wrow);
      f32x4 whi = *(const f32x4*)(wrow + 4);
      short8 bf;
      bf[0] = f2bf(wlo.x); bf[1] = f2bf(wlo.y);
      bf[2] = f2bf(wlo.z); bf[3] = f2bf(wlo.w);
      bf[4] = f2bf(whi.x); bf[5] = f2bf(whi.y);
      bf[6] = f2bf(whi.z); bf[7] = f2bf(whi.w);
      acc[nf] = __builtin_amdgcn_mfma_f32_16x16x32_bf16(af, bf, acc[nf], 0, 0, 0);
    }
  }

#pragma unroll
  for (int i = 0; i < 4; ++i) {
    const int orow = rowbase + kg * 4 + i;
    if (orow >= R) continue;
    const float* addrow = add ? add + (long long)orow * C128 : nullptr;
    const float* grow = gidx ? gtab + (long long)gidx[orow] * C128 : nullptr;
    float* orow_p = out + (long long)orow * C128;
#pragma unroll
    for (int nf = 0; nf < 8; ++nf) {
      const int oc = nf * 16 + r16;
      float v = acc[nf][i];
      if (addrow) v += addrow[oc];
      if (grow)   v += grow[oc];
      orow_p[oc] = v;
    }
  }
}

// histogram: cnt[cl[i]]++ (int atomics on L2-resident, distributed counters)
__global__ __launch_bounds__(256) void hist_kernel(
    const int* __restrict__ cl, int* __restrict__ cnt, int n)
{
  int i = blockIdx.x * blockDim.x + threadIdx.x;
  const int stride = gridDim.x * blockDim.x;
  for (; i < n; i += stride) atomicAdd(&cnt[cl[i]], 1);
}

// offsets via wave-prefix-scan + ONE atomic per wave on the shared cursor.
// (R3 lesson: per-thread atomicAdd(tot, c) with VARIABLE c from 1e5 threads on
// one address serializes at the L2 bank -> ~hundreds of µs. Wave scan makes it
// 1563 atomics.) Segment ordering is arbitrary but off/cur are consistent.
__global__ __launch_bounds__(256) void scan_kernel(
    const int* __restrict__ cnt, int* __restrict__ off, int* __restrict__ cur,
    int* __restrict__ tot, int n)
{
  const int i    = blockIdx.x * blockDim.x + threadIdx.x;
  const int lane = threadIdx.x & 63;

  int c = (i < n) ? cnt[i] : 0;

  // inclusive scan across the 64-lane wave
  int pref = c;
#pragma unroll
  for (int d = 1; d < 64; d <<= 1) {
    int t = __shfl_up(pref, d);
    if (lane >= d) pref += t;
  }
  const int wave_total = __shfl(pref, 63);

  int base = 0;
  if (lane == 63) base = atomicAdd(tot, wave_total);
  base = __shfl(base, 63);

  if (i < n) {
    const int o = base + (pref - c);  // exclusive prefix + wave base
    off[i] = o;
    cur[i] = o;
  }
}

// fill member lists: idx[cur[cl[i]]++] = i
__global__ __launch_bounds__(256) void fill_kernel(
    const int* __restrict__ cl, int* __restrict__ cur, int* __restrict__ idx, int n)
{
  int i = blockIdx.x * blockDim.x + threadIdx.x;
  const int stride = gridDim.x * blockDim.x;
  for (; i < n; i += stride) {
    int p = atomicAdd(&cur[cl[i]], 1);
    idx[p] = i;
  }
}

// One wave per cluster: gather member rows, accumulate in registers, write mean.
// FUSE_Y: also write y[i] = x[i] + t[cluster] (t row loaded once per wave).
// Lane owns columns {2*lane, 2*lane+1} (f32x2, 512B/row fully coalesced).
template<bool FUSE_Y>
__global__ __launch_bounds__(256) void cluster_reduce(
    const float* __restrict__ x, const int* __restrict__ idx,
    const int* __restrict__ off, const int* __restrict__ cnt,
    const float* __restrict__ t, float* __restrict__ y,
    float* __restrict__ mean, int nc)
{
  const int wid  = blockIdx.x * (blockDim.x >> 6) + (threadIdx.x >> 6);
  const int lane = threadIdx.x & 63;
  if (wid >= nc) return;

  const int n = cnt[wid];
  const int o = off[wid];

  f32x2 s = {0.f, 0.f};
  f32x2 tc = {0.f, 0.f};
  if (FUSE_Y) tc = ((const f32x2*)(t + (long long)wid * C128))[lane];

  for (int m = 0; m < n; ++m) {
    const int i = idx[o + m];
    f32x2 xv = ((const f32x2*)(x + (long long)i * C128))[lane];
    s += xv;
    if (FUSE_Y) ((f32x2*)(y + (long long)i * C128))[lane] = xv + tc;
  }

  const float invn = n > 0 ? 1.0f / (float)n : 0.0f;
  ((f32x2*)(mean + (long long)wid * C128))[lane] = s * invn;
}

extern "C" void kernel_launch(void* const* d_in, const int* in_sizes, int n_in,
                              void* d_out, int out_size, void* d_ws, size_t ws_size,
                              hipStream_t stream)
{
  const float* x0 = (const float*)d_in[0];
  const float* x1 = (const float*)d_in[1];
  const float* x2 = (const float*)d_in[2];
  const int* cluster1 = (const int*)d_in[3];
  const int* cluster2 = (const int*)d_in[4];
  const float* Wf2c0 = (const float*)d_in[5];
  const float* Wf2c1 = (const float*)d_in[6];
  const float* Wc2f0 = (const float*)d_in[7];
  const float* Wc2f1 = (const float*)d_in[8];

  const int N0 = in_sizes[0] / C128;
  const int N1 = in_sizes[1] / C128;
  const int N2 = in_sizes[2] / C128;

  float* y0 = (float*)d_out;
  float* y1 = y0 + (long long)N0 * C128;
  float* y2 = y1 + (long long)N1 * C128;

  // means live in-place in the output regions (finalize GEMM is in-place safe)
  float* mean0 = y1;
  float* mean1 = y2;

  // workspace layout (4B units):
  // [t1: N1*128][t2: N2*128][cnt0: N1][cnt1: N2][tot: 2][off0: N1][off1: N2]
  // [cur0: N1][cur1: N2][idx0: N0][idx1: N1]   (~61.5 MB total)
  float* t1 = (float*)d_ws;
  float* t2 = t1 + (long long)N1 * C128;
  int* cnt0 = (int*)(t2 + (long long)N2 * C128);
  int* cnt1 = cnt0 + N1;
  int* tot  = cnt1 + N2;           // 2 counters
  int* off0 = tot + 2;
  int* off1 = off0 + N1;
  int* cur0 = off1 + N2;
  int* cur1 = cur0 + N1;
  int* idx0 = cur1 + N2;
  int* idx1 = idx0 + N0;

  // zero cnt0, cnt1, tot (contiguous)
  hipMemsetAsync(cnt0, 0, (size_t)(N1 + N2 + 2) * 4, stream);

  // t1 = x1 @ Wc2f0^T ; t2 = x2 @ Wc2f1^T  (independent of CSR build)
  gemm_wt_fused<<<(N1 + 63) / 64, 256, 0, stream>>>(
      x1, Wc2f0, nullptr, nullptr, nullptr, t1, N1);
  gemm_wt_fused<<<(N2 + 63) / 64, 256, 0, stream>>>(
      x2, Wc2f1, nullptr, nullptr, nullptr, t2, N2);

  // CSR build for cluster1 (N0 -> N1) and cluster2 (N1 -> N2)
  {
    int b0 = (N0 + 255) / 256; if (b0 > 2048) b0 = 2048;
    int b1 = (N1 + 255) / 256; if (b1 > 2048) b1 = 2048;
    hist_kernel<<<b0, 256, 0, stream>>>(cluster1, cnt0, N0);
    hist_kernel<<<b1, 256, 0, stream>>>(cluster2, cnt1, N1);
    scan_kernel<<<(N1 + 255) / 256, 256, 0, stream>>>(cnt0, off0, cur0, tot + 0, N1);
    scan_kernel<<<(N2 + 255) / 256, 256, 0, stream>>>(cnt1, off1, cur1, tot + 1, N2);
    fill_kernel<<<b0, 256, 0, stream>>>(cluster1, cur0, idx0, N0);
    fill_kernel<<<b1, 256, 0, stream>>>(cluster2, cur1, idx1, N1);
  }

  // one wave per cluster: (nc+3)/4 blocks of 256
  // big fused pass: y0 = x0 + t1[cluster1] and mean0 = segment_mean(x0)
  cluster_reduce<true><<<(N1 + 3) / 4, 256, 0, stream>>>(
      x0, idx0, off0, cnt0, t1, y0, mean0, N1);
  // small pass: mean1 = segment_mean(x1)
  cluster_reduce<false><<<(N2 + 3) / 4, 256, 0, stream>>>(
      x1, idx1, off1, cnt1, nullptr, nullptr, mean1, N2);

  // y1 = mean0 @ Wf2c0^T + x1 + t2[cluster2]   (in-place: A == out == y1 region)
  gemm_wt_fused<<<(N1 + 63) / 64, 256, 0, stream>>>(
      mean0, Wf2c0, x1, cluster2, t2, y1, N1);
  // y2 = mean1 @ Wf2c1^T + x2                   (in-place: A == out == y2 region)
  gemm_wt_fused<<<(N2 + 63) / 64, 256, 0, stream>>>(
      mean1, Wf2c1, x2, nullptr, nullptr, y2, N2);
}

// Round 5
// 564.449 us; speedup vs baseline: 1.1865x; 1.1865x over previous
//
#include <hip/hip_runtime.h>

#define C128 128

typedef __attribute__((ext_vector_type(2))) float f32x2;
typedef __attribute__((ext_vector_type(4))) float f32x4;
typedef __attribute__((ext_vector_type(8))) short short8;

// f32 -> bf16 round-to-nearest-even (finite inputs)
__device__ __forceinline__ short f2bf(float f) {
  union { float f; unsigned u; } v; v.f = f;
  unsigned r = (v.u + 0x7fffu + ((v.u >> 16) & 1u)) >> 16;
  return (short)r;
}

// out[r][j] = sum_k A[r][k]*W[j][k] (+add[r][j]) (+gtab[gidx[r]][j])
// 64 rows/block, 4 waves, wave owns 16 rows x 128 cols. MFMA 16x16x32 bf16.
// In-place safe for out==A (wave reads only the 16 rows it writes; reads precede stores).
__device__ __forceinline__ void gemm_body(
    const float* __restrict__ A, const float* __restrict__ W,
    const float* __restrict__ add,
    const int* __restrict__ gidx, const float* __restrict__ gtab,
    float* __restrict__ out, int R, int blockrow)
{
  const int tid  = threadIdx.x;
  const int wave = tid >> 6;
  const int lane = tid & 63;
  const int r16  = lane & 15;
  const int kg   = lane >> 4;

  const int rowbase = blockrow + wave * 16;
  if (rowbase >= R) return;
  const int arow_i  = rowbase + r16;
  const int lrow    = arow_i < R ? arow_i : (R - 1);  // clamp; garbage never stored

  f32x4 acc[8];
#pragma unroll
  for (int i = 0; i < 8; ++i) acc[i] = (f32x4){0.f, 0.f, 0.f, 0.f};

  const float* arow = A + (long long)lrow * C128;

#pragma unroll
  for (int ks = 0; ks < 4; ++ks) {
    const int k0 = ks * 32 + kg * 8;
    f32x4 alo = *(const f32x4*)(arow + k0);
    f32x4 ahi = *(const f32x4*)(arow + k0 + 4);
    short8 af;
    af[0] = f2bf(alo.x); af[1] = f2bf(alo.y);
    af[2] = f2bf(alo.z); af[3] = f2bf(alo.w);
    af[4] = f2bf(ahi.x); af[5] = f2bf(ahi.y);
    af[6] = f2bf(ahi.z); af[7] = f2bf(ahi.w);
#pragma unroll
    for (int nf = 0; nf < 8; ++nf) {
      const float* wrow = W + (nf * 16 + r16) * C128 + k0;
      f32x4 wlo = *(const f32x4*)(wrow);
      f32x4 whi = *(const f32x4*)(wrow + 4);
      short8 bf;
      bf[0] = f2bf(wlo.x); bf[1] = f2bf(wlo.y);
      bf[2] = f2bf(wlo.z); bf[3] = f2bf(wlo.w);
      bf[4] = f2bf(whi.x); bf[5] = f2bf(whi.y);
      bf[6] = f2bf(whi.z); bf[7] = f2bf(whi.w);
      acc[nf] = __builtin_amdgcn_mfma_f32_16x16x32_bf16(af, bf, acc[nf], 0, 0, 0);
    }
  }

#pragma unroll
  for (int i = 0; i < 4; ++i) {
    const int orow = rowbase + kg * 4 + i;
    if (orow >= R) continue;
    const float* addrow = add ? add + (long long)orow * C128 : nullptr;
    const float* grow = gidx ? gtab + (long long)gidx[orow] * C128 : nullptr;
    float* orow_p = out + (long long)orow * C128;
#pragma unroll
    for (int nf = 0; nf < 8; ++nf) {
      const int oc = nf * 16 + r16;
      float v = acc[nf][i];
      if (addrow) v += addrow[oc];
      if (grow)   v += grow[oc];
      orow_p[oc] = v;
    }
  }
}

// pre: zero a slice of the counter region, then t1 = x1@W1^T / t2 = x2@W2^T
__global__ __launch_bounds__(256) void pre_gemm(
    const float* __restrict__ x1, const float* __restrict__ W1, float* __restrict__ t1, int n1,
    const float* __restrict__ x2, const float* __restrict__ W2, float* __restrict__ t2, int n2,
    int* __restrict__ zbuf, int zlen, int B1)
{
  // zero cnt0/cnt1/tot (completes before this kernel ends; hist launches after)
  {
    const int nb  = gridDim.x;
    const int per = (zlen + nb - 1) / nb;
    const int zs  = blockIdx.x * per;
    const int ze  = (zs + per < zlen) ? zs + per : zlen;
    for (int k = zs + threadIdx.x; k < ze; k += 256) zbuf[k] = 0;
  }
  if ((int)blockIdx.x < B1)
    gemm_body(x1, W1, nullptr, nullptr, nullptr, t1, n1, blockIdx.x * 64);
  else
    gemm_body(x2, W2, nullptr, nullptr, nullptr, t2, n2, (blockIdx.x - B1) * 64);
}

// post: y1 = mean0@Wf2c0^T + x1 + t2[cluster2] ; y2 = mean1@Wf2c1^T + x2 (in-place A==out)
__global__ __launch_bounds__(256) void post_gemm(
    const float* __restrict__ mean0, const float* __restrict__ Wa,
    const float* __restrict__ x1, const int* __restrict__ cluster2,
    const float* __restrict__ t2, float* __restrict__ y1, int n1,
    const float* __restrict__ mean1, const float* __restrict__ Wb,
    const float* __restrict__ x2, float* __restrict__ y2, int n2, int B1)
{
  if ((int)blockIdx.x < B1)
    gemm_body(mean0, Wa, x1, cluster2, t2, y1, n1, blockIdx.x * 64);
  else
    gemm_body(mean1, Wb, x2, nullptr, nullptr, y2, n2, (blockIdx.x - B1) * 64);
}

// merged histogram over both cluster arrays
__global__ __launch_bounds__(256) void hist2(
    const int* __restrict__ cl1, int n0, int* __restrict__ cnt0,
    const int* __restrict__ cl2, int n1, int* __restrict__ cnt1)
{
  int i = blockIdx.x * blockDim.x + threadIdx.x;
  const int stride = gridDim.x * blockDim.x;
  const int total = n0 + n1;
  for (; i < total; i += stride) {
    if (i < n0) atomicAdd(&cnt0[cl1[i]], 1);
    else        atomicAdd(&cnt1[cl2[i - n0]], 1);
  }
}

// merged offsets: wave-prefix-scan + one atomic per wave on the region cursor.
// Regions 256-aligned so a wave never straddles.
__global__ __launch_bounds__(256) void scan2(
    const int* __restrict__ cnt0, int* __restrict__ off0, int* __restrict__ cur0, int n1,
    const int* __restrict__ cnt1, int* __restrict__ off1, int* __restrict__ cur1, int n2,
    int* __restrict__ tot)
{
  const int p1 = (n1 + 255) & ~255;
  const int i  = blockIdx.x * blockDim.x + threadIdx.x;
  const int lane = threadIdx.x & 63;

  const int* cnt; int* off; int* cur; int* t; int j; int nn;
  if (i < p1) { cnt = cnt0; off = off0; cur = cur0; t = tot + 0; j = i;      nn = n1; }
  else        { cnt = cnt1; off = off1; cur = cur1; t = tot + 1; j = i - p1; nn = n2; }

  int c = (j < nn) ? cnt[j] : 0;
  int pref = c;
#pragma unroll
  for (int d = 1; d < 64; d <<= 1) {
    int v = __shfl_up(pref, d);
    if (lane >= d) pref += v;
  }
  const int wave_total = __shfl(pref, 63);
  int base = 0;
  if (lane == 63) base = atomicAdd(t, wave_total);
  base = __shfl(base, 63);

  if (j < nn) {
    const int o = base + (pref - c);
    off[j] = o;
    cur[j] = o;
  }
}

// merged member-list fill
__global__ __launch_bounds__(256) void fill2(
    const int* __restrict__ cl1, int n0, int* __restrict__ cur0, int* __restrict__ idx0,
    const int* __restrict__ cl2, int n1, int* __restrict__ cur1, int* __restrict__ idx1)
{
  int i = blockIdx.x * blockDim.x + threadIdx.x;
  const int stride = gridDim.x * blockDim.x;
  const int total = n0 + n1;
  for (; i < total; i += stride) {
    if (i < n0) { int p = atomicAdd(&cur0[cl1[i]], 1); idx0[p] = i; }
    else        { int k = i - n0; int p = atomicAdd(&cur1[cl2[k]], 1); idx1[p] = k; }
  }
}

// One wave per cluster, both scales in one launch.
// wid < n1: big pass on x0 (y0 = x0 + t1[wid] fused, mean -> mean0)
// wid >= n1: small pass on x1 (mean -> mean1)
// idx values prefetched lane-parallel, broadcast via __shfl; 2-way unrolled body
// keeps two 512B row loads in flight per wave.
__global__ __launch_bounds__(256) void cluster_reduce2(
    const float* __restrict__ x0, const int* __restrict__ idx0,
    const int* __restrict__ off0, const int* __restrict__ cnt0,
    const float* __restrict__ t1, float* __restrict__ y0,
    float* __restrict__ mean0, int n1,
    const float* __restrict__ x1, const int* __restrict__ idx1,
    const int* __restrict__ off1, const int* __restrict__ cnt1,
    float* __restrict__ mean1, int n2)
{
  int wid = blockIdx.x * 4 + (threadIdx.x >> 6);
  const int lane = threadIdx.x & 63;
  if (wid >= n1 + n2) return;

  const float* x; const int* idxp; const int* offp; const int* cntp;
  float* meanp; const float* trow = nullptr; float* yb = nullptr;
  if (wid < n1) {
    x = x0; idxp = idx0; offp = off0; cntp = cnt0; meanp = mean0;
    trow = t1 + (long long)wid * C128; yb = y0;
  } else {
    wid -= n1;
    x = x1; idxp = idx1; offp = off1; cntp = cnt1; meanp = mean1;
  }

  const int n = cntp[wid];
  const int o = offp[wid];

  f32x2 tc = {0.f, 0.f};
  if (trow) tc = ((const f32x2*)trow)[lane];

  f32x2 s0 = {0.f, 0.f}, s1 = {0.f, 0.f};
  for (int base = 0; base < n; base += 64) {
    const int m = (n - base < 64) ? (n - base) : 64;
    int vi = (lane < m) ? idxp[o + base + lane] : 0;
    int j = 0;
    for (; j + 1 < m; j += 2) {
      const long long i0 = __shfl(vi, j);
      const long long i1 = __shfl(vi, j + 1);
      f32x2 a = ((const f32x2*)(x + i0 * C128))[lane];
      f32x2 b = ((const f32x2*)(x + i1 * C128))[lane];
      s0 += a; s1 += b;
      if (yb) {
        ((f32x2*)(yb + i0 * C128))[lane] = a + tc;
        ((f32x2*)(yb + i1 * C128))[lane] = b + tc;
      }
    }
    if (j < m) {
      const long long i0 = __shfl(vi, j);
      f32x2 a = ((const f32x2*)(x + i0 * C128))[lane];
      s0 += a;
      if (yb) ((f32x2*)(yb + i0 * C128))[lane] = a + tc;
    }
  }

  const float invn = n > 0 ? 1.0f / (float)n : 0.0f;
  ((f32x2*)(meanp + (long long)wid * C128))[lane] = (s0 + s1) * invn;
}

extern "C" void kernel_launch(void* const* d_in, const int* in_sizes, int n_in,
                              void* d_out, int out_size, void* d_ws, size_t ws_size,
                              hipStream_t stream)
{
  const float* x0 = (const float*)d_in[0];
  const float* x1 = (const float*)d_in[1];
  const float* x2 = (const float*)d_in[2];
  const int* cluster1 = (const int*)d_in[3];
  const int* cluster2 = (const int*)d_in[4];
  const float* Wf2c0 = (const float*)d_in[5];
  const float* Wf2c1 = (const float*)d_in[6];
  const float* Wc2f0 = (const float*)d_in[7];
  const float* Wc2f1 = (const float*)d_in[8];

  const int N0 = in_sizes[0] / C128;
  const int N1 = in_sizes[1] / C128;
  const int N2 = in_sizes[2] / C128;

  float* y0 = (float*)d_out;
  float* y1 = y0 + (long long)N0 * C128;
  float* y2 = y1 + (long long)N1 * C128;

  // means in-place in output regions (post_gemm is in-place safe)
  float* mean0 = y1;
  float* mean1 = y2;

  // ws: [t1: N1*128][t2: N2*128][cnt0: N1][cnt1: N2][tot: 2][off0: N1][off1: N2]
  //     [cur0: N1][cur1: N2][idx0: N0][idx1: N1]
  float* t1 = (float*)d_ws;
  float* t2 = t1 + (long long)N1 * C128;
  int* cnt0 = (int*)(t2 + (long long)N2 * C128);
  int* cnt1 = cnt0 + N1;
  int* tot  = cnt1 + N2;
  int* off0 = tot + 2;
  int* off1 = off0 + N1;
  int* cur0 = off1 + N2;
  int* cur1 = cur0 + N1;
  int* idx0 = cur1 + N2;
  int* idx1 = idx0 + N0;

  const int B1 = (N1 + 63) / 64;
  const int B2 = (N2 + 63) / 64;

  // 1. pre: zero cnt0/cnt1/tot + t1 = x1@Wc2f0^T, t2 = x2@Wc2f1^T
  pre_gemm<<<B1 + B2, 256, 0, stream>>>(
      x1, Wc2f0, t1, N1, x2, Wc2f1, t2, N2, cnt0, N1 + N2 + 2, B1);

  // 2-4. CSR build, merged per stage
  int bh = (N0 + N1 + 255) / 256; if (bh > 2048) bh = 2048;
  hist2<<<bh, 256, 0, stream>>>(cluster1, N0, cnt0, cluster2, N1, cnt1);
  const int p1 = (N1 + 255) & ~255, p2 = (N2 + 255) & ~255;
  scan2<<<(p1 + p2) / 256, 256, 0, stream>>>(
      cnt0, off0, cur0, N1, cnt1, off1, cur1, N2, tot);
  fill2<<<bh, 256, 0, stream>>>(cluster1, N0, cur0, idx0, cluster2, N1, cur1, idx1);

  // 5. both segment-means (+ fused y0) in one launch; one wave per cluster
  cluster_reduce2<<<(N1 + N2 + 3) / 4, 256, 0, stream>>>(
      x0, idx0, off0, cnt0, t1, y0, mean0, N1,
      x1, idx1, off1, cnt1, mean1, N2);

  // 6. post: y1, y2
  post_gemm<<<B1 + B2, 256, 0, stream>>>(
      mean0, Wf2c0, x1, cluster2, t2, y1, N1,
      mean1, Wf2c1, x2, y2, N2, B1);
}